// Round 1
// baseline (24748.045 us; speedup 1.0000x reference)
//
#include <hip/hip_runtime.h>
#include <hip/hip_bf16.h>

#define T_STEPS 4096
#define BATCH 8
#define DIN 512
#define NH 512
#define G4 2048
#define NBLK 32
#define JPB 16

typedef __attribute__((ext_vector_type(8))) short bf16x8;
typedef __attribute__((ext_vector_type(4))) float f32x4;

struct U128 { unsigned long long a, b; };

__device__ __forceinline__ unsigned short f2b(float f) {
  __hip_bfloat16 h = __float2bfloat16(f);
  return __builtin_bit_cast(unsigned short, h);
}
__device__ __forceinline__ float b2f(unsigned short u) {
  unsigned int x = ((unsigned int)u) << 16;
  return __builtin_bit_cast(float, x);
}
__device__ __forceinline__ float sigf(float x) { return 1.f / (1.f + __expf(-x)); }
__device__ __forceinline__ float tanh_fast(float x) { return 1.f - 2.f / (1.f + __expf(2.f * x)); }

// ---------------- init: flags=0, hbuf[0]=bf16(h0), hbuf[1]=0, pad rows 8..15 = 0
__global__ __launch_bounds__(512) void init_ws(const float* __restrict__ h0,
                                               unsigned int* __restrict__ flags,
                                               unsigned int* __restrict__ hbuf) {
  int tid = threadIdx.x;
  if (tid < 32) flags[tid] = 0u;
  for (int i = tid; i < 8192; i += 512) {   // [2][16][256] u32
    unsigned int v = 0u;
    if (i < 4096) {
      int row = i >> 8, col = i & 255;
      if (row < 8) {
        int j = col << 1;
        v = ((unsigned int)f2b(h0[row * NH + j + 1]) << 16) | f2b(h0[row * NH + j]);
      }
    }
    hbuf[i] = v;
  }
}

// ---------------- XI = x @ Wi + (bi + bh), stored bf16 [32768][2048]
#define BM 64
#define BN 64
#define BK 16
__global__ __launch_bounds__(256) void xi_gemm(const float* __restrict__ x,
                                               const float* __restrict__ Wi,
                                               const float* __restrict__ bi,
                                               const float* __restrict__ bh,
                                               unsigned short* __restrict__ xi) {
  __shared__ float As[BK][BM + 4];
  __shared__ float Bs[BK][BN + 4];
  const int tid = threadIdx.x;
  const int m0 = blockIdx.x * BM;
  const int n0 = blockIdx.y * BN;
  const int tx = tid & 15, ty = tid >> 4;
  const int arow = tid & 63, ak = (tid >> 6) << 2;
  const int bk = tid >> 4, bn = (tid & 15) << 2;
  float acc[4][4] = {};
  for (int k0 = 0; k0 < DIN; k0 += BK) {
    float4 av = *(const float4*)(x + (size_t)(m0 + arow) * DIN + k0 + ak);
    float4 bv = *(const float4*)(Wi + (size_t)(k0 + bk) * G4 + n0 + bn);
    __syncthreads();
    As[ak + 0][arow] = av.x;
    As[ak + 1][arow] = av.y;
    As[ak + 2][arow] = av.z;
    As[ak + 3][arow] = av.w;
    *(float4*)&Bs[bk][bn] = bv;
    __syncthreads();
#pragma unroll
    for (int kk = 0; kk < BK; ++kk) {
      float am[4], bw[4];
      *(float4*)am = *(const float4*)&As[kk][ty << 2];
      *(float4*)bw = *(const float4*)&Bs[kk][tx << 2];
#pragma unroll
      for (int i = 0; i < 4; ++i)
#pragma unroll
        for (int j = 0; j < 4; ++j) acc[i][j] = fmaf(am[i], bw[j], acc[i][j]);
    }
  }
#pragma unroll
  for (int i = 0; i < 4; ++i) {
    int m = m0 + (ty << 2) + i;
#pragma unroll
    for (int j = 0; j < 4; j += 2) {
      int n = n0 + (tx << 2) + j;
      float v0 = acc[i][j] + bi[n] + bh[n];
      float v1 = acc[i][j + 1] + bi[n + 1] + bh[n + 1];
      unsigned int pk = ((unsigned int)f2b(v1) << 16) | f2b(v0);
      *(unsigned int*)(xi + (size_t)m * G4 + n) = pk;
    }
  }
}

// ---------------- persistent recurrent kernel: 32 blocks x 512 threads (8 waves)
// block owns j in [blk*16, blk*16+16); wave w: gate = w>>1, k-half = w&1.
__global__ __launch_bounds__(512) void lstm_rec(const float* __restrict__ Wh,
                                                const float* __restrict__ h0c0,
                                                const unsigned short* __restrict__ xi,
                                                float* __restrict__ out,
                                                unsigned int* __restrict__ flags,
                                                unsigned int* __restrict__ hbuf32) {
  const int blk = blockIdx.x;
  const int j0 = blk * JPB;
  const int tid = threadIdx.x;
  const int lane = tid & 63;
  const int w = tid >> 6;
  const int gate = w >> 1;
  const int kh = w & 1;

  __shared__ float prebuf[8][32][4];
  __shared__ float houtS[128];
  __shared__ float cellS[128];

  // Preload B fragments (Wh slice -> bf16, registers). B[k][n]: n = lane&15 (+colbase),
  // k = kh*256 + m*32 + (lane>>4)*8 + e  (same k-mapping used for A-frags -> layout-consistent).
  bf16x8 bw[8];
  {
    const int col = gate * NH + j0 + (lane & 15);
    const int kb = kh * 256 + ((lane >> 4) << 3);
#pragma unroll
    for (int m = 0; m < 8; ++m) {
      bf16x8 v;
#pragma unroll
      for (int e = 0; e < 8; ++e) {
        float wv = Wh[(size_t)(kb + m * 32 + e) * G4 + col];
        v[e] = (short)f2b(wv);
      }
      bw[m] = v;
    }
  }
  if (tid < 128) {
    int b = tid >> 4, jl = tid & 15;
    cellS[tid] = h0c0[(BATCH + b) * NH + j0 + jl];   // hidden0[1] = c0
  }
  __syncthreads();

  const unsigned long long* hq = (const unsigned long long*)hbuf32; // [2][16][128] u64
  const int arow = lane & 15;
  const int akb = kh * 256 + ((lane >> 4) << 3);

  const int cmb_b = tid >> 4, cmb_j = tid & 15;   // combine ids (tid < 128)
  const int cl = ((cmb_b >> 2) << 4) + cmb_j;     // source lane in C-frag
  const int cq = cmb_b & 3;                       // source reg

  for (int t = 0; t < T_STEPS; ++t) {
    // XI prefetch -> MFMA acc init (matches verified C/D layout: row b=(lane>>4)*4+q, col=lane&15)
    f32x4 acc0 = {0.f, 0.f, 0.f, 0.f};
    if (kh == 0 && lane < 32) {
      const int c = gate * NH + j0 + (lane & 15);
      const int brow = (lane >> 4) << 2;
      const size_t base = ((size_t)t * BATCH + brow) * G4 + c;
#pragma unroll
      for (int q = 0; q < 4; ++q) acc0[q] = b2f(xi[base + (size_t)q * G4]);
    }
    // wait for h(t): monotonic per-block epoch flags
    if (w == 0) {
      const int fidx = lane & 31;
      unsigned int v;
      do {
        v = __hip_atomic_load(&flags[fidx], __ATOMIC_RELAXED, __HIP_MEMORY_SCOPE_AGENT);
      } while (!__all((int)(v >= (unsigned int)t)));
    }
    __syncthreads();

    // A-frags straight from global h-buffer (agent-scope loads -> LLC-coherent), 8 MFMAs, 2 chains
    const unsigned long long* hb =
        hq + ((size_t)(t & 1) * 16 * 128) + (size_t)arow * 128 + (akb >> 2);
    f32x4 acc1 = {0.f, 0.f, 0.f, 0.f};
#pragma unroll
    for (int m = 0; m < 8; m += 2) {
      unsigned long long q0 = __hip_atomic_load(hb + m * 8 + 0, __ATOMIC_RELAXED, __HIP_MEMORY_SCOPE_AGENT);
      unsigned long long q1 = __hip_atomic_load(hb + m * 8 + 1, __ATOMIC_RELAXED, __HIP_MEMORY_SCOPE_AGENT);
      unsigned long long q2 = __hip_atomic_load(hb + m * 8 + 8, __ATOMIC_RELAXED, __HIP_MEMORY_SCOPE_AGENT);
      unsigned long long q3 = __hip_atomic_load(hb + m * 8 + 9, __ATOMIC_RELAXED, __HIP_MEMORY_SCOPE_AGENT);
      bf16x8 a0 = __builtin_bit_cast(bf16x8, U128{q0, q1});
      bf16x8 a1 = __builtin_bit_cast(bf16x8, U128{q2, q3});
      acc0 = __builtin_amdgcn_mfma_f32_16x16x32_bf16(a0, bw[m], acc0, 0, 0, 0);
      acc1 = __builtin_amdgcn_mfma_f32_16x16x32_bf16(a1, bw[m + 1], acc1, 0, 0, 0);
    }
    if (lane < 32) {
      f32x4 s = acc0 + acc1;
#pragma unroll
      for (int q = 0; q < 4; ++q) prebuf[w][lane][q] = s[q];
    }
    __syncthreads();

    // combine k-halves + gates + state update (threads 0..127 = one (b,j) each)
    if (tid < 128) {
      float pf = prebuf[0][cl][cq] + prebuf[1][cl][cq];
      float pi = prebuf[2][cl][cq] + prebuf[3][cl][cq];
      float po = prebuf[4][cl][cq] + prebuf[5][cl][cq];
      float pg = prebuf[6][cl][cq] + prebuf[7][cl][cq];
      float fg = sigf(pf), ig = sigf(pi), og = sigf(po), gg = tanh_fast(pg);
      float cn = fg * cellS[tid] + ig * gg;
      cellS[tid] = cn;
      float h = og * tanh_fast(cn);
      out[((size_t)t * BATCH + cmb_b) * NH + j0 + cmb_j] = h;
      houtS[tid] = h;
    }
    __syncthreads();

    // publish h(t+1) slice (wave 0: 64 lanes x bf16x2) + release flag
    if (w == 0) {
      const int pb = lane >> 3, pj = (lane & 7) << 1;
      unsigned int pk = ((unsigned int)f2b(houtS[pb * 16 + pj + 1]) << 16) |
                        f2b(houtS[pb * 16 + pj]);
      const int idx = (((t + 1) & 1) << 12) + (pb << 8) + ((j0 + pj) >> 1);
      __hip_atomic_store(&hbuf32[idx], pk, __ATOMIC_RELAXED, __HIP_MEMORY_SCOPE_AGENT);
      if (lane == 0)
        __hip_atomic_store(&flags[blk], (unsigned int)(t + 1), __ATOMIC_RELEASE,
                           __HIP_MEMORY_SCOPE_AGENT);
    }
  }

  // final state tail: [h_T ; c_T]
  if (tid < 128) {
    const size_t tail = (size_t)T_STEPS * BATCH * NH;
    out[tail + (size_t)cmb_b * NH + j0 + cmb_j] = houtS[tid];
    out[tail + (size_t)BATCH * NH + (size_t)cmb_b * NH + j0 + cmb_j] = cellS[tid];
  }
}

extern "C" void kernel_launch(void* const* d_in, const int* in_sizes, int n_in,
                              void* d_out, int out_size, void* d_ws, size_t ws_size,
                              hipStream_t stream) {
  const float* x  = (const float*)d_in[0];
  const float* h0 = (const float*)d_in[1];
  const float* Wi = (const float*)d_in[2];
  const float* bi = (const float*)d_in[3];
  const float* Wh = (const float*)d_in[4];
  const float* bh = (const float*)d_in[5];
  float* out = (float*)d_out;

  // ws layout: [0,128) flags | [256, 256+32KB) hbuf [2][16][512]bf16 | [64KB, +128MB) XI bf16
  unsigned int* flags = (unsigned int*)d_ws;
  unsigned int* hbuf  = (unsigned int*)((char*)d_ws + 256);
  unsigned short* xi  = (unsigned short*)((char*)d_ws + 65536);

  init_ws<<<1, 512, 0, stream>>>(h0, flags, hbuf);
  dim3 g1((T_STEPS * BATCH) / BM, G4 / BN);
  xi_gemm<<<g1, 256, 0, stream>>>(x, Wi, bi, bh, xi);
  lstm_rec<<<NBLK, 512, 0, stream>>>(Wh, h0, xi, out, flags, hbuf);
}